// Round 8
// baseline (134.639 us; speedup 1.0000x reference)
//
#include <hip/hip_runtime.h>
#include <math.h>

#define D_MODEL 768
#define HS 64
#define BATCH 8
#define SEQ 2048
// Q is pre-scaled by 0.125*log2(e) in proj's epilogue (fp32), so attn
// computes P = 2^(Qs . K) with a single v_exp_f32 and no extra muls.
#define QSCALE_LOG2E 0.1803368801f
#define KSPLIT 8
#define KCHUNK (SEQ / KSPLIT)   // 256
#define PM 32                   // proj M-tile -> grid 512

typedef _Float16 half_t;
typedef __attribute__((ext_vector_type(8))) _Float16 half8;
typedef __attribute__((ext_vector_type(4))) float floatx4;

// async global->LDS, 16B per lane, lane-linear LDS destination
typedef const __attribute__((address_space(1))) void gas_void;
typedef __attribute__((address_space(3))) void las_void;
__device__ __forceinline__ void gl_lds16(const void* g, void* l) {
    __builtin_amdgcn_global_load_lds((gas_void*)g, (las_void*)l, 16, 0, 0);
}
__device__ __forceinline__ void waitcnt_all() {
    __builtin_amdgcn_s_waitcnt(0);
}
__device__ __forceinline__ float fast_exp2(float x) {
#if __has_builtin(__builtin_amdgcn_exp2f)
    return __builtin_amdgcn_exp2f(x);
#else
    return exp2f(x);
#endif
}

// ---------------------------------------------------------------
// Kernel 1: W fp32 [D][H] x3 -> Wt fp16 [3*H][D], via coalesced
// 64x64 LDS transpose. Grid 36 = 3 matrices x 12 k-tiles.
// ---------------------------------------------------------------
__global__ __launch_bounds__(256)
void wconv_kernel(const float* __restrict__ Wq, const float* __restrict__ Wk,
                  const float* __restrict__ Wv, half_t* __restrict__ Wt)
{
    __shared__ float lds[64][65];
    const int m = blockIdx.x / 12;
    const int k0 = (blockIdx.x % 12) * 64;
    const float* W = (m == 0) ? Wq : ((m == 1) ? Wk : Wv);
    const int tid = threadIdx.x;
#pragma unroll
    for (int ri = 0; ri < 4; ++ri) {
        int row = ri * 16 + (tid >> 4);
        int col = (tid & 15) * 4;
        float4 v = *(const float4*)(W + (size_t)(k0 + row) * HS + col);
        lds[row][col] = v.x; lds[row][col + 1] = v.y;
        lds[row][col + 2] = v.z; lds[row][col + 3] = v.w;
    }
    __syncthreads();
#pragma unroll
    for (int i = 0; i < 2; ++i) {
        int idx = i * 256 + tid;
        int h = idx >> 3;
        int kc = idx & 7;
        half8 o;
#pragma unroll
        for (int j = 0; j < 8; ++j) o[j] = (half_t)lds[kc * 8 + j][h];
        *(half8*)(Wt + (size_t)(m * HS + h) * D_MODEL + k0 + kc * 8) = o;
    }
}

// ---------------------------------------------------------------
// Kernel 2: QKV projection. M=32 x N=192 tile (grid 512), parity
// double-buffered LDS, ONE barrier/iter, register prefetch after
// the barrier. Q rows pre-scaled by 0.125*log2e (fp32).
// ---------------------------------------------------------------
__global__ __launch_bounds__(256)
void proj_kernel(const float* __restrict__ x, const half_t* __restrict__ Wt,
                 const float* __restrict__ bq, const float* __restrict__ bk,
                 const float* __restrict__ bv,
                 half_t* __restrict__ Qh, half_t* __restrict__ Kh,
                 half_t* __restrict__ Vt)
{
    __shared__ __align__(16) half_t xs[2][PM * 64];    // 2 x 4 KB
    __shared__ __align__(16) half_t wtl[2][192 * 64];  // 2 x 24 KB

    const int tid = threadIdx.x;
    const int w = tid >> 6;
    const int lane = tid & 63;
    const int l15 = lane & 15;
    const int quad = lane >> 4;
    const long row0 = (long)blockIdx.x * PM;

    floatx4 acc[2][3];
#pragma unroll
    for (int i = 0; i < 2; ++i)
#pragma unroll
        for (int j = 0; j < 3; ++j) acc[i][j] = (floatx4){0.f, 0.f, 0.f, 0.f};

    float4 xA[2], xB[2];
    half8  wA[6], wB[6];

    auto loadx = [&](int k0, float4 (&v)[2]) {
        int r = tid >> 3, sc = tid & 7;
        int cg = sc ^ (r & 7);
        const float* p = x + (row0 + r) * D_MODEL + k0 + cg * 8;
        v[0] = *(const float4*)p;
        v[1] = *(const float4*)(p + 4);
    };
    auto loadw = [&](int k0, half8 (&wr)[6]) {
#pragma unroll
        for (int i = 0; i < 6; ++i) {
            int idx = i * 256 + tid;
            int r = idx >> 3, sc = idx & 7;
            int cg = sc ^ (r & 7);
            wr[i] = *(const half8*)(Wt + (size_t)r * D_MODEL + k0 + cg * 8);
        }
    };

    auto step = [&](int it, float4 (&xc)[2], half8 (&wc)[6],
                    float4 (&xn)[2], half8 (&wn)[6], int p) {
        {
            float4 a = xc[0], b = xc[1];
            half8 xh = (half8){(half_t)a.x, (half_t)a.y, (half_t)a.z, (half_t)a.w,
                               (half_t)b.x, (half_t)b.y, (half_t)b.z, (half_t)b.w};
            *(half8*)&xs[p][tid * 8] = xh;
        }
#pragma unroll
        for (int i = 0; i < 6; ++i)
            *(half8*)&wtl[p][(i * 256 + tid) * 8] = wc[i];
        __syncthreads();                 // buf p staged across all waves
        // prefetch next tile AFTER barrier -> covered by the MFMA phase
        int kn = (it + 1 < 12) ? (it + 1) * 64 : 0;
        loadx(kn, xn);
        loadw(kn, wn);
#pragma unroll
        for (int kst = 0; kst < 2; ++kst) {
            half8 af[2];
#pragma unroll
            for (int mt = 0; mt < 2; ++mt) {
                int r = mt * 16 + l15;
                int slot = (kst * 4 + quad) ^ (r & 7);
                af[mt] = *(const half8*)&xs[p][r * 64 + slot * 8];
            }
#pragma unroll
            for (int nt = 0; nt < 3; ++nt) {
                int r = w * 48 + nt * 16 + l15;
                int slot = (kst * 4 + quad) ^ (r & 7);
                half8 bf = *(const half8*)&wtl[p][r * 64 + slot * 8];
#pragma unroll
                for (int mt = 0; mt < 2; ++mt)
                    acc[mt][nt] = __builtin_amdgcn_mfma_f32_16x16x32_f16(
                        af[mt], bf, acc[mt][nt], 0, 0, 0);
            }
        }
    };

    loadx(0, xA);
    loadw(0, wA);
#pragma unroll
    for (int it = 0; it < 12; it += 2) {
        step(it,     xA, wA, xB, wB, 0);
        step(it + 1, xB, wB, xA, wA, 1);
    }

    // epilogue: bias (+ Q pre-scale) + fp16 store
#pragma unroll
    for (int nt = 0; nt < 3; ++nt) {
        int nbase = w * 48 + nt * 16;
        int mm = nbase >> 6;
        int h = (nbase + l15) & 63;
        const float* bias = (mm == 0) ? bq : ((mm == 1) ? bk : bv);
        float bval = bias[h];
#pragma unroll
        for (int mt = 0; mt < 2; ++mt)
#pragma unroll
            for (int r = 0; r < 4; ++r) {
                long R = row0 + mt * 16 + quad * 4 + r;
                float fv = acc[mt][nt][r] + bval;
                if (mm == 0) {
                    Qh[R * HS + h] = (half_t)(fv * QSCALE_LOG2E);
                } else if (mm == 1) {
                    Kh[R * HS + h] = (half_t)fv;
                } else {
                    long bb = R >> 11, s = R & 2047;
                    Vt[(bb * HS + h) * SEQ + s] = (half_t)fv;
                }
            }
    }
}

// ---------------------------------------------------------------
// Kernel 3: flash attention. 2-wave blocks (128 thr, 64 q/wave),
// grid (16,8,8)=1024. K double-buffered via gl_lds; V direct from
// global (L2-resident). Swapped QK^T (mfma(K,Q)) with sigma row
// remap: QK tile t's A-rows are K rows
//   sigma(t,l15) = (t>>1)*32 + (l15>>2)*8 + (t&1)*4 + (l15&3)
// so the output lands at kk = kst*32 + quad*8 + u*4 + r — i.e. the
// packed exp2 results ARE the PV A-fragment, lane-local. Zero LDS
// and zero shuffles in the softmax path (R7's shfl mapping was
// unsatisfiable: one src lane would have to feed two words/instr).
// Swizzle key changed to (r&3)|((r>>1)&4) on BOTH stage and read
// (rule 21) -> still 2-way (free) bank conflicts. LDS 16.4 KB.
// ---------------------------------------------------------------
__global__ __launch_bounds__(128)
void attn_kernel(const half_t* __restrict__ Qh, const half_t* __restrict__ Kh,
                 const half_t* __restrict__ Vt,
                 half_t* __restrict__ Opart, float* __restrict__ lpart)
{
    __shared__ __align__(16) half_t ks[2][64 * 64];   // 2 x 8 KB [kk][h] swizzled

    const int tid = threadIdx.x;
    const int w = tid >> 6;
    const int lane = tid & 63;
    const int l15 = lane & 15;
    const int quad = lane >> 4;
    const int b = blockIdx.y;
    const int q0 = blockIdx.x * 128 + w * 64;
    const int kh = blockIdx.z;
    const int kk_begin = kh * KCHUNK;

    const half_t* Kb = Kh + (size_t)b * SEQ * HS;
    const half_t* Vb = Vt + (size_t)b * HS * SEQ;

    // stage K tile into buf p: swizzle key = (r&3)|((r>>1)&4)
    auto stage = [&](int p, int kk0) {
#pragma unroll
        for (int i = 0; i < 4; ++i) {
            int idx = i * 128 + tid;
            int r = idx >> 3, sc = idx & 7;
            int key = (r & 3) | ((r >> 1) & 4);
            int cg = sc ^ key;
            gl_lds16(Kb + (size_t)(kk0 + r) * HS + cg * 8, &ks[p][idx * 8]);
        }
    };

    stage(0, kk_begin);                    // K tile 0 in flight first

    half8 qf[4][2];
#pragma unroll
    for (int mt = 0; mt < 4; ++mt)
#pragma unroll
        for (int hst = 0; hst < 2; ++hst)
            qf[mt][hst] = *(const half8*)(Qh + ((size_t)b * SEQ + q0 + mt * 16 + l15) * HS
                                          + hst * 32 + quad * 8);

    floatx4 oacc[4][4];
    float lsum[4];                         // per-lane: q = mt*16 + l15
#pragma unroll
    for (int mt = 0; mt < 4; ++mt) {
#pragma unroll
        for (int nt = 0; nt < 4; ++nt) oacc[mt][nt] = (floatx4){0.f, 0.f, 0.f, 0.f};
        lsum[mt] = 0.f;
    }

    for (int it = 0; it < KCHUNK / 64; ++it) {
        const int cur = it & 1;
        const int kk0 = kk_begin + it * 64;
        waitcnt_all();     // this thread's async K writes landed
        __syncthreads();   // tile visible; WAR fence for buf cur^1
        if (it + 1 < KCHUNK / 64)
            stage(cur ^ 1, kk0 + 64);      // next K tile flies under compute

        // V-fragments direct from global (L2-hit), issued early so the
        // QK^T + softmax phase hides their latency
        half8 vf[4][2];
#pragma unroll
        for (int nt = 0; nt < 4; ++nt)
#pragma unroll
            for (int kst = 0; kst < 2; ++kst)
                vf[nt][kst] = *(const half8*)(Vb + (size_t)(nt * 16 + l15) * SEQ
                                              + kk0 + kst * 32 + quad * 8);

        // K fragments with sigma row remap (shared by both q-halves)
        half8 kfr[4][2];
#pragma unroll
        for (int t = 0; t < 4; ++t) {
            int r = ((t >> 1) << 5) | ((l15 >> 2) << 3) | ((t & 1) << 2) | (l15 & 3);
            int key = (r & 3) | ((r >> 1) & 4);
#pragma unroll
            for (int hst = 0; hst < 2; ++hst) {
                int slot = (hst * 4 + quad) ^ key;
                kfr[t][hst] = *(const half8*)&ks[cur][r * 64 + slot * 8];
            }
        }

#pragma unroll
        for (int h2 = 0; h2 < 2; ++h2) {
            // swapped QK^T: sacc[mtl][t][r] = P[kk = (t>>1)*32 + quad*8
            //   + (t&1)*4 + r][q = (h2*2+mtl)*16 + l15]
            floatx4 sacc[2][4];
#pragma unroll
            for (int mtl = 0; mtl < 2; ++mtl)
#pragma unroll
                for (int t = 0; t < 4; ++t) sacc[mtl][t] = (floatx4){0.f, 0.f, 0.f, 0.f};
#pragma unroll
            for (int t = 0; t < 4; ++t)
#pragma unroll
                for (int hst = 0; hst < 2; ++hst)
#pragma unroll
                    for (int mtl = 0; mtl < 2; ++mtl)
                        sacc[mtl][t] = __builtin_amdgcn_mfma_f32_16x16x32_f16(
                            kfr[t][hst], qf[h2 * 2 + mtl][hst], sacc[mtl][t], 0, 0, 0);

#pragma unroll
            for (int mtl = 0; mtl < 2; ++mtl) {
                int mt = h2 * 2 + mtl;
                // exp2 + in-lane lsum + pack: pk[kst*4 + u*2 + pr] holds
                // kk-pair kst*32 + quad*8 + u*4 + 2*pr — exactly the PV
                // A-fragment layout (row=q=l15, k=quad*8+j).
                union { int i[4]; half8 h; } pa[2];
#pragma unroll
                for (int t = 0; t < 4; ++t)
#pragma unroll
                    for (int pr = 0; pr < 2; ++pr) {
                        float p0 = fast_exp2(sacc[mtl][t][pr * 2]);
                        float p1 = fast_exp2(sacc[mtl][t][pr * 2 + 1]);
                        lsum[mt] += p0 + p1;
                        union { _Float16 hh[2]; int ii; } u;
                        u.hh[0] = (half_t)p0;
                        u.hh[1] = (half_t)p1;
                        pa[t >> 1].i[(t & 1) * 2 + pr] = u.ii;
                    }
#pragma unroll
                for (int kst = 0; kst < 2; ++kst)
#pragma unroll
                    for (int nt = 0; nt < 4; ++nt)
                        oacc[mt][nt] = __builtin_amdgcn_mfma_f32_16x16x32_f16(
                            pa[kst].h, vf[nt][kst], oacc[mt][nt], 0, 0, 0);
            }
        }
    }

    // reduce lsum across the 4 quads (same l15 = same q row)
#pragma unroll
    for (int mt = 0; mt < 4; ++mt) {
        float s = lsum[mt];
        s += __shfl_xor(s, 16);
        s += __shfl_xor(s, 32);
        lsum[mt] = s;
    }

    size_t obase = ((size_t)kh * BATCH + b) * SEQ * HS;
#pragma unroll
    for (int mt = 0; mt < 4; ++mt)
#pragma unroll
        for (int nt = 0; nt < 4; ++nt)
#pragma unroll
            for (int r = 0; r < 4; ++r) {
                int row = q0 + mt * 16 + quad * 4 + r;
                Opart[obase + (size_t)row * HS + nt * 16 + l15] = (half_t)oacc[mt][nt][r];
            }
    if (lane < 16) {
#pragma unroll
        for (int mt = 0; mt < 4; ++mt) {
            int row = q0 + mt * 16 + l15;
            lpart[((size_t)kh * BATCH + b) * SEQ + row] = lsum[mt];
        }
    }
}

// ---------------------------------------------------------------
// Kernel 4: combine KSPLIT partials: out = sum(O_i) / sum(l_i)
// ---------------------------------------------------------------
__global__ __launch_bounds__(256)
void combine_kernel(const half_t* __restrict__ Opart, const float* __restrict__ lpart,
                    float* __restrict__ out)
{
    const size_t NT = (size_t)BATCH * SEQ * HS;
    const size_t BS = (size_t)BATCH * SEQ;
    size_t e0 = ((size_t)blockIdx.x * 256 + threadIdx.x) * 8;
    size_t row = e0 / HS;
    float o[8] = {0, 0, 0, 0, 0, 0, 0, 0};
    float l = 0.f;
#pragma unroll
    for (int i = 0; i < KSPLIT; ++i) {
        half8 oi = *(const half8*)(Opart + (size_t)i * NT + e0);
#pragma unroll
        for (int j = 0; j < 8; ++j) o[j] += (float)oi[j];
        l += lpart[(size_t)i * BS + row];
    }
    float inv = 1.f / l;
    float4 a = {o[0] * inv, o[1] * inv, o[2] * inv, o[3] * inv};
    float4 c = {o[4] * inv, o[5] * inv, o[6] * inv, o[7] * inv};
    *(float4*)(out + e0) = a;
    *(float4*)(out + e0 + 4) = c;
}

extern "C" void kernel_launch(void* const* d_in, const int* in_sizes, int n_in,
                              void* d_out, int out_size, void* d_ws, size_t ws_size,
                              hipStream_t stream) {
    const float* x  = (const float*)d_in[0];
    const float* Wq = (const float*)d_in[1];
    const float* bq = (const float*)d_in[2];
    const float* Wk = (const float*)d_in[3];
    const float* bk = (const float*)d_in[4];
    const float* Wv = (const float*)d_in[5];
    const float* bv = (const float*)d_in[6];
    float* out = (float*)d_out;

    const size_t per = (size_t)BATCH * SEQ * HS;      // 1,048,576 elements
    half_t* Qh = (half_t*)d_ws;
    half_t* Kh = Qh + per;
    half_t* Vt = Kh + per;
    half_t* Wt = Vt + per;                            // 147,456 halfs
    half_t* Opart = Wt + 3 * HS * D_MODEL;
    float*  lpart = (float*)(Opart + (size_t)KSPLIT * per);   // ~23 MB total

    wconv_kernel<<<dim3(36), dim3(256), 0, stream>>>(Wq, Wk, Wv, Wt);
    proj_kernel<<<dim3(BATCH * SEQ / PM), dim3(256), 0, stream>>>(
        x, Wt, bq, bk, bv, Qh, Kh, Vt);
    attn_kernel<<<dim3(SEQ / 128, BATCH, KSPLIT), dim3(128), 0, stream>>>(
        Qh, Kh, Vt, Opart, lpart);
    combine_kernel<<<dim3((BATCH * SEQ * HS) / (256 * 8)), dim3(256), 0, stream>>>(
        Opart, lpart, out);
}

// Round 9
// 132.786 us; speedup vs baseline: 1.0140x; 1.0140x over previous
//
#include <hip/hip_runtime.h>
#include <math.h>

#define D_MODEL 768
#define HS 64
#define BATCH 8
#define SEQ 2048
// Q is pre-scaled by 0.125*log2(e) in proj's epilogue (fp32), so attn
// computes P = 2^(Qs . K) with a single v_exp_f32 and no extra muls.
#define QSCALE_LOG2E 0.1803368801f
#define KSPLIT 8
#define KCHUNK (SEQ / KSPLIT)   // 256
#define PM 32                   // proj M-tile -> grid 512

typedef _Float16 half_t;
typedef __attribute__((ext_vector_type(8))) _Float16 half8;
typedef __attribute__((ext_vector_type(4))) float floatx4;

// async global->LDS, 16B per lane, lane-linear LDS destination
typedef const __attribute__((address_space(1))) void gas_void;
typedef __attribute__((address_space(3))) void las_void;
__device__ __forceinline__ void gl_lds16(const void* g, void* l) {
    __builtin_amdgcn_global_load_lds((gas_void*)g, (las_void*)l, 16, 0, 0);
}
__device__ __forceinline__ void waitcnt_all() {
    __builtin_amdgcn_s_waitcnt(0);
}
__device__ __forceinline__ float fast_exp2(float x) {
#if __has_builtin(__builtin_amdgcn_exp2f)
    return __builtin_amdgcn_exp2f(x);
#else
    return exp2f(x);
#endif
}

// ---------------------------------------------------------------
// Kernel 1: W fp32 [D][H] x3 -> Wt fp16 [3*H][D], via coalesced
// 64x64 LDS transpose. Grid 36 = 3 matrices x 12 k-tiles.
// ---------------------------------------------------------------
__global__ __launch_bounds__(256)
void wconv_kernel(const float* __restrict__ Wq, const float* __restrict__ Wk,
                  const float* __restrict__ Wv, half_t* __restrict__ Wt)
{
    __shared__ float lds[64][65];
    const int m = blockIdx.x / 12;
    const int k0 = (blockIdx.x % 12) * 64;
    const float* W = (m == 0) ? Wq : ((m == 1) ? Wk : Wv);
    const int tid = threadIdx.x;
#pragma unroll
    for (int ri = 0; ri < 4; ++ri) {
        int row = ri * 16 + (tid >> 4);
        int col = (tid & 15) * 4;
        float4 v = *(const float4*)(W + (size_t)(k0 + row) * HS + col);
        lds[row][col] = v.x; lds[row][col + 1] = v.y;
        lds[row][col + 2] = v.z; lds[row][col + 3] = v.w;
    }
    __syncthreads();
#pragma unroll
    for (int i = 0; i < 2; ++i) {
        int idx = i * 256 + tid;
        int h = idx >> 3;
        int kc = idx & 7;
        half8 o;
#pragma unroll
        for (int j = 0; j < 8; ++j) o[j] = (half_t)lds[kc * 8 + j][h];
        *(half8*)(Wt + (size_t)(m * HS + h) * D_MODEL + k0 + kc * 8) = o;
    }
}

// ---------------------------------------------------------------
// Kernel 2: QKV projection. M=32 x N=192 tile (grid 512), parity
// double-buffered LDS. W staging now via global_load_lds (was the
// R0-era global->VGPR->LDS round-trip, Common-mistake #1 / m97's
// +67% lever): per k-step, cvt+store x -> waitcnt -> barrier ->
// issue next W gl_lds + x reg prefetch -> 12 MFMA. LDS image is
// byte-identical to the old path (same pre-swizzled global source,
// same lane-linear dest), so the compute side is unchanged.
// ---------------------------------------------------------------
__global__ __launch_bounds__(256)
void proj_kernel(const float* __restrict__ x, const half_t* __restrict__ Wt,
                 const float* __restrict__ bq, const float* __restrict__ bk,
                 const float* __restrict__ bv,
                 half_t* __restrict__ Qh, half_t* __restrict__ Kh,
                 half_t* __restrict__ Vt)
{
    __shared__ __align__(16) half_t xs[2][PM * 64];    // 2 x 4 KB
    __shared__ __align__(16) half_t wtl[2][192 * 64];  // 2 x 24 KB

    const int tid = threadIdx.x;
    const int w = tid >> 6;
    const int lane = tid & 63;
    const int l15 = lane & 15;
    const int quad = lane >> 4;
    const long row0 = (long)blockIdx.x * PM;

    floatx4 acc[2][3];
#pragma unroll
    for (int i = 0; i < 2; ++i)
#pragma unroll
        for (int j = 0; j < 3; ++j) acc[i][j] = (floatx4){0.f, 0.f, 0.f, 0.f};

    float4 xA[2], xB[2];

    auto loadx = [&](int k0, float4 (&v)[2]) {
        int r = tid >> 3, sc = tid & 7;
        int cg = sc ^ (r & 7);
        const float* p = x + (row0 + r) * D_MODEL + k0 + cg * 8;
        v[0] = *(const float4*)p;
        v[1] = *(const float4*)(p + 4);
    };
    // async W stage: same global pre-swizzle, lane-linear LDS dest
    auto stage_w = [&](int p, int k0) {
#pragma unroll
        for (int i = 0; i < 6; ++i) {
            int idx = i * 256 + tid;
            int r = idx >> 3, sc = idx & 7;
            int cg = sc ^ (r & 7);
            gl_lds16(Wt + (size_t)r * D_MODEL + k0 + cg * 8, &wtl[p][idx * 8]);
        }
    };

    auto step = [&](int it, float4 (&xc)[2], float4 (&xn)[2], int p) {
        // stage current x tile into buf p (cvt in regs)
        {
            float4 a = xc[0], b = xc[1];
            half8 xh = (half8){(half_t)a.x, (half_t)a.y, (half_t)a.z, (half_t)a.w,
                               (half_t)b.x, (half_t)b.y, (half_t)b.z, (half_t)b.w};
            *(half8*)&xs[p][tid * 8] = xh;
        }
        waitcnt_all();                   // this wave's W gl_lds (tile it) landed
        __syncthreads();                 // xs[p]+wtl[p] visible to all waves;
                                         // WAR-safe for buf p^1 (program order)
        // prefetch next tile AFTER barrier -> covered by the MFMA phase
        int kn = (it + 1 < 12) ? (it + 1) * 64 : 0;
        if (it + 1 < 12) stage_w(p ^ 1, kn);
        loadx(kn, xn);
#pragma unroll
        for (int kst = 0; kst < 2; ++kst) {
            half8 af[2];
#pragma unroll
            for (int mt = 0; mt < 2; ++mt) {
                int r = mt * 16 + l15;
                int slot = (kst * 4 + quad) ^ (r & 7);
                af[mt] = *(const half8*)&xs[p][r * 64 + slot * 8];
            }
#pragma unroll
            for (int nt = 0; nt < 3; ++nt) {
                int r = w * 48 + nt * 16 + l15;
                int slot = (kst * 4 + quad) ^ (r & 7);
                half8 bf = *(const half8*)&wtl[p][r * 64 + slot * 8];
#pragma unroll
                for (int mt = 0; mt < 2; ++mt)
                    acc[mt][nt] = __builtin_amdgcn_mfma_f32_16x16x32_f16(
                        af[mt], bf, acc[mt][nt], 0, 0, 0);
            }
        }
    };

    stage_w(0, 0);                       // W tile 0 in flight
    loadx(0, xA);
#pragma unroll
    for (int it = 0; it < 12; it += 2) {
        step(it,     xA, xB, 0);
        step(it + 1, xB, xA, 1);
    }

    // epilogue: bias (+ Q pre-scale) + fp16 store
#pragma unroll
    for (int nt = 0; nt < 3; ++nt) {
        int nbase = w * 48 + nt * 16;
        int mm = nbase >> 6;
        int h = (nbase + l15) & 63;
        const float* bias = (mm == 0) ? bq : ((mm == 1) ? bk : bv);
        float bval = bias[h];
#pragma unroll
        for (int mt = 0; mt < 2; ++mt)
#pragma unroll
            for (int r = 0; r < 4; ++r) {
                long R = row0 + mt * 16 + quad * 4 + r;
                float fv = acc[mt][nt][r] + bval;
                if (mm == 0) {
                    Qh[R * HS + h] = (half_t)(fv * QSCALE_LOG2E);
                } else if (mm == 1) {
                    Kh[R * HS + h] = (half_t)fv;
                } else {
                    long bb = R >> 11, s = R & 2047;
                    Vt[(bb * HS + h) * SEQ + s] = (half_t)fv;
                }
            }
    }
}

// ---------------------------------------------------------------
// Kernel 3: flash attention (R8, unchanged). 2-wave blocks, grid
// (16,8,8). K dbuf via gl_lds; V direct from global; swapped QK^T
// with sigma row remap so packed exp2 results ARE the PV A-frag.
// Zero LDS and zero shuffles in softmax; 0 bank conflicts (R8).
// ---------------------------------------------------------------
__global__ __launch_bounds__(128)
void attn_kernel(const half_t* __restrict__ Qh, const half_t* __restrict__ Kh,
                 const half_t* __restrict__ Vt,
                 half_t* __restrict__ Opart, float* __restrict__ lpart)
{
    __shared__ __align__(16) half_t ks[2][64 * 64];   // 2 x 8 KB [kk][h] swizzled

    const int tid = threadIdx.x;
    const int w = tid >> 6;
    const int lane = tid & 63;
    const int l15 = lane & 15;
    const int quad = lane >> 4;
    const int b = blockIdx.y;
    const int q0 = blockIdx.x * 128 + w * 64;
    const int kh = blockIdx.z;
    const int kk_begin = kh * KCHUNK;

    const half_t* Kb = Kh + (size_t)b * SEQ * HS;
    const half_t* Vb = Vt + (size_t)b * HS * SEQ;

    // stage K tile into buf p: swizzle key = (r&3)|((r>>1)&4)
    auto stage = [&](int p, int kk0) {
#pragma unroll
        for (int i = 0; i < 4; ++i) {
            int idx = i * 128 + tid;
            int r = idx >> 3, sc = idx & 7;
            int key = (r & 3) | ((r >> 1) & 4);
            int cg = sc ^ key;
            gl_lds16(Kb + (size_t)(kk0 + r) * HS + cg * 8, &ks[p][idx * 8]);
        }
    };

    stage(0, kk_begin);                    // K tile 0 in flight first

    half8 qf[4][2];
#pragma unroll
    for (int mt = 0; mt < 4; ++mt)
#pragma unroll
        for (int hst = 0; hst < 2; ++hst)
            qf[mt][hst] = *(const half8*)(Qh + ((size_t)b * SEQ + q0 + mt * 16 + l15) * HS
                                          + hst * 32 + quad * 8);

    floatx4 oacc[4][4];
    float lsum[4];                         // per-lane: q = mt*16 + l15
#pragma unroll
    for (int mt = 0; mt < 4; ++mt) {
#pragma unroll
        for (int nt = 0; nt < 4; ++nt) oacc[mt][nt] = (floatx4){0.f, 0.f, 0.f, 0.f};
        lsum[mt] = 0.f;
    }

    for (int it = 0; it < KCHUNK / 64; ++it) {
        const int cur = it & 1;
        const int kk0 = kk_begin + it * 64;
        waitcnt_all();     // this thread's async K writes landed
        __syncthreads();   // tile visible; WAR fence for buf cur^1
        if (it + 1 < KCHUNK / 64)
            stage(cur ^ 1, kk0 + 64);      // next K tile flies under compute

        // V-fragments direct from global (L2-hit), issued early so the
        // QK^T + softmax phase hides their latency
        half8 vf[4][2];
#pragma unroll
        for (int nt = 0; nt < 4; ++nt)
#pragma unroll
            for (int kst = 0; kst < 2; ++kst)
                vf[nt][kst] = *(const half8*)(Vb + (size_t)(nt * 16 + l15) * SEQ
                                              + kk0 + kst * 32 + quad * 8);

        // K fragments with sigma row remap (shared by both q-halves)
        half8 kfr[4][2];
#pragma unroll
        for (int t = 0; t < 4; ++t) {
            int r = ((t >> 1) << 5) | ((l15 >> 2) << 3) | ((t & 1) << 2) | (l15 & 3);
            int key = (r & 3) | ((r >> 1) & 4);
#pragma unroll
            for (int hst = 0; hst < 2; ++hst) {
                int slot = (hst * 4 + quad) ^ key;
                kfr[t][hst] = *(const half8*)&ks[cur][r * 64 + slot * 8];
            }
        }

#pragma unroll
        for (int h2 = 0; h2 < 2; ++h2) {
            // swapped QK^T: sacc[mtl][t][r] = P[kk = (t>>1)*32 + quad*8
            //   + (t&1)*4 + r][q = (h2*2+mtl)*16 + l15]
            floatx4 sacc[2][4];
#pragma unroll
            for (int mtl = 0; mtl < 2; ++mtl)
#pragma unroll
                for (int t = 0; t < 4; ++t) sacc[mtl][t] = (floatx4){0.f, 0.f, 0.f, 0.f};
#pragma unroll
            for (int t = 0; t < 4; ++t)
#pragma unroll
                for (int hst = 0; hst < 2; ++hst)
#pragma unroll
                    for (int mtl = 0; mtl < 2; ++mtl)
                        sacc[mtl][t] = __builtin_amdgcn_mfma_f32_16x16x32_f16(
                            kfr[t][hst], qf[h2 * 2 + mtl][hst], sacc[mtl][t], 0, 0, 0);

#pragma unroll
            for (int mtl = 0; mtl < 2; ++mtl) {
                int mt = h2 * 2 + mtl;
                // exp2 + in-lane lsum + pack: pa[kst].i[u*2+pr] holds
                // kk-pair kst*32 + quad*8 + u*4 + 2*pr — exactly the PV
                // A-fragment layout (row=q=l15, k=quad*8+j).
                union { int i[4]; half8 h; } pa[2];
#pragma unroll
                for (int t = 0; t < 4; ++t)
#pragma unroll
                    for (int pr = 0; pr < 2; ++pr) {
                        float p0 = fast_exp2(sacc[mtl][t][pr * 2]);
                        float p1 = fast_exp2(sacc[mtl][t][pr * 2 + 1]);
                        lsum[mt] += p0 + p1;
                        union { _Float16 hh[2]; int ii; } u;
                        u.hh[0] = (half_t)p0;
                        u.hh[1] = (half_t)p1;
                        pa[t >> 1].i[(t & 1) * 2 + pr] = u.ii;
                    }
#pragma unroll
                for (int kst = 0; kst < 2; ++kst)
#pragma unroll
                    for (int nt = 0; nt < 4; ++nt)
                        oacc[mt][nt] = __builtin_amdgcn_mfma_f32_16x16x32_f16(
                            pa[kst].h, vf[nt][kst], oacc[mt][nt], 0, 0, 0);
            }
        }
    }

    // reduce lsum across the 4 quads (same l15 = same q row)
#pragma unroll
    for (int mt = 0; mt < 4; ++mt) {
        float s = lsum[mt];
        s += __shfl_xor(s, 16);
        s += __shfl_xor(s, 32);
        lsum[mt] = s;
    }

    size_t obase = ((size_t)kh * BATCH + b) * SEQ * HS;
#pragma unroll
    for (int mt = 0; mt < 4; ++mt)
#pragma unroll
        for (int nt = 0; nt < 4; ++nt)
#pragma unroll
            for (int r = 0; r < 4; ++r) {
                int row = q0 + mt * 16 + quad * 4 + r;
                Opart[obase + (size_t)row * HS + nt * 16 + l15] = (half_t)oacc[mt][nt][r];
            }
    if (lane < 16) {
#pragma unroll
        for (int mt = 0; mt < 4; ++mt) {
            int row = q0 + mt * 16 + l15;
            lpart[((size_t)kh * BATCH + b) * SEQ + row] = lsum[mt];
        }
    }
}

// ---------------------------------------------------------------
// Kernel 4: combine KSPLIT partials: out = sum(O_i) / sum(l_i)
// ---------------------------------------------------------------
__global__ __launch_bounds__(256)
void combine_kernel(const half_t* __restrict__ Opart, const float* __restrict__ lpart,
                    float* __restrict__ out)
{
    const size_t NT = (size_t)BATCH * SEQ * HS;
    const size_t BS = (size_t)BATCH * SEQ;
    size_t e0 = ((size_t)blockIdx.x * 256 + threadIdx.x) * 8;
    size_t row = e0 / HS;
    float o[8] = {0, 0, 0, 0, 0, 0, 0, 0};
    float l = 0.f;
#pragma unroll
    for (int i = 0; i < KSPLIT; ++i) {
        half8 oi = *(const half8*)(Opart + (size_t)i * NT + e0);
#pragma unroll
        for (int j = 0; j < 8; ++j) o[j] += (float)oi[j];
        l += lpart[(size_t)i * BS + row];
    }
    float inv = 1.f / l;
    float4 a = {o[0] * inv, o[1] * inv, o[2] * inv, o[3] * inv};
    float4 c = {o[4] * inv, o[5] * inv, o[6] * inv, o[7] * inv};
    *(float4*)(out + e0) = a;
    *(float4*)(out + e0 + 4) = c;
}

extern "C" void kernel_launch(void* const* d_in, const int* in_sizes, int n_in,
                              void* d_out, int out_size, void* d_ws, size_t ws_size,
                              hipStream_t stream) {
    const float* x  = (const float*)d_in[0];
    const float* Wq = (const float*)d_in[1];
    const float* bq = (const float*)d_in[2];
    const float* Wk = (const float*)d_in[3];
    const float* bk = (const float*)d_in[4];
    const float* Wv = (const float*)d_in[5];
    const float* bv = (const float*)d_in[6];
    float* out = (float*)d_out;

    const size_t per = (size_t)BATCH * SEQ * HS;      // 1,048,576 elements
    half_t* Qh = (half_t*)d_ws;
    half_t* Kh = Qh + per;
    half_t* Vt = Kh + per;
    half_t* Wt = Vt + per;                            // 147,456 halfs
    half_t* Opart = Wt + 3 * HS * D_MODEL;
    float*  lpart = (float*)(Opart + (size_t)KSPLIT * per);   // ~23 MB total

    wconv_kernel<<<dim3(36), dim3(256), 0, stream>>>(Wq, Wk, Wv, Wt);
    proj_kernel<<<dim3(BATCH * SEQ / PM), dim3(256), 0, stream>>>(
        x, Wt, bq, bk, bv, Qh, Kh, Vt);
    attn_kernel<<<dim3(SEQ / 128, BATCH, KSPLIT), dim3(128), 0, stream>>>(
        Qh, Kh, Vt, Opart, lpart);
    combine_kernel<<<dim3((BATCH * SEQ * HS) / (256 * 8)), dim3(256), 0, stream>>>(
        Opart, lpart, out);
}